// Round 4
// baseline (250.817 us; speedup 1.0000x reference)
//
#include <hip/hip_runtime.h>
#include <hip/hip_bf16.h>
#include <hip/hip_fp16.h>
#include <stdint.h>

typedef __bf16 bf16_t;
typedef __bf16 bf16x8 __attribute__((ext_vector_type(8)));
typedef float f32x4 __attribute__((ext_vector_type(4)));

typedef __attribute__((address_space(1))) void gv_t;
typedef __attribute__((address_space(3))) void lv_t;

__device__ inline unsigned short f2bf_bits(float f) {
  uint32_t u = __float_as_uint(f);
  u += 0x7FFFu + ((u >> 16) & 1u);   // RNE
  return (unsigned short)(u >> 16);
}
__device__ inline bf16_t f2bf(float f) {
  unsigned short h = f2bf_bits(f);
  return __builtin_bit_cast(bf16_t, h);
}

__device__ inline void storeC(float* p, float v) { *p = v; }
__device__ inline void storeC(bf16_t* p, float v) { *p = f2bf(v); }
__device__ inline void storeC(__half* p, float v) { *p = __float2half(v); }

// ---------------------------------------------------------------------------
// fp32 -> bf16 conversion for x, Wq, Wk (packed together), Wv
// ---------------------------------------------------------------------------
__global__ __launch_bounds__(256)
void convert_all(const float* __restrict__ x, const float* __restrict__ wq,
                 const float* __restrict__ wk, const float* __restrict__ wv,
                 bf16_t* __restrict__ xb, bf16_t* __restrict__ wqkb,
                 bf16_t* __restrict__ wvb)
{
  const int64_t NX = 8192LL * 1024, NW = 1024LL * 1024;
  const int64_t total4 = (NX + 3 * NW) >> 2;
  for (int64_t i = (int64_t)blockIdx.x * blockDim.x + threadIdx.x; i < total4;
       i += (int64_t)gridDim.x * blockDim.x) {
    int64_t e = i << 2;
    const float* src; bf16_t* dst; int64_t off;
    if (e < NX)               { src = x;  dst = xb;         off = e; }
    else if (e < NX + NW)     { src = wq; dst = wqkb;       off = e - NX; }
    else if (e < NX + 2 * NW) { src = wk; dst = wqkb + NW;  off = e - NX - NW; }
    else                      { src = wv; dst = wvb;        off = e - NX - 2 * NW; }
    float4 f = *(const float4*)(src + off);
    uint32_t lo = ((uint32_t)f2bf_bits(f.y) << 16) | f2bf_bits(f.x);
    uint32_t hi = ((uint32_t)f2bf_bits(f.w) << 16) | f2bf_bits(f.z);
    *(uint2*)(dst + off) = make_uint2(lo, hi);
  }
}

// ---------------------------------------------------------------------------
// Legacy 128x128 2-phase gemm (kept for the small Vt projection only).
// ---------------------------------------------------------------------------
template <typename OUT_T>
__global__ __launch_bounds__(256)
void gemm_bt(const bf16_t* __restrict__ A, const bf16_t* __restrict__ B,
             OUT_T* __restrict__ C, int K, int lda, int ldb, int ldc,
             int64_t b_batch_stride, int bm_per_batch)
{
  __shared__ bf16_t As[2][128 * 32];
  __shared__ bf16_t Bs[2][128 * 32];
  const int tid  = threadIdx.x;
  const int wid  = tid >> 6;
  const int lane = tid & 63;
  const int wm = wid >> 1, wn = wid & 1;
  const int64_t bm = blockIdx.x;
  const int64_t bn = blockIdx.y;

  const bf16_t* Bb = B + (bm / bm_per_batch) * b_batch_stride;

  const int c0row = (wid * 2 + 0) * 16 + (lane >> 2);
  const int c1row = (wid * 2 + 1) * 16 + (lane >> 2);
  const int scol  = (lane & 3) * 8;

  const bf16_t* Ar0 = A  + (bm * 128 + c0row) * lda + scol;
  const bf16_t* Ar1 = A  + (bm * 128 + c1row) * lda + scol;
  const bf16_t* Br0 = Bb + (bn * 128 + c0row) * ldb + scol;
  const bf16_t* Br1 = Bb + (bn * 128 + c1row) * ldb + scol;

  const int ad0 = (wid * 2 + 0) * 512;
  const int ad1 = (wid * 2 + 1) * 512;

  const int frow = lane & 15;
  const int fk   = (lane >> 4) * 8;
  const int aoff = (wm * 64 + frow) * 32 + fk;
  const int boff = (wn * 64 + frow) * 32 + fk;

  f32x4 acc[4][4];
  #pragma unroll
  for (int m = 0; m < 4; m++)
    #pragma unroll
    for (int n = 0; n < 4; n++) acc[m][n] = f32x4{0.f, 0.f, 0.f, 0.f};

  auto stage = [&](int buf, int k0) {
    __builtin_amdgcn_global_load_lds((const gv_t*)(Ar0 + k0),
                                     (lv_t*)(&As[buf][ad0]), 16, 0, 0);
    __builtin_amdgcn_global_load_lds((const gv_t*)(Ar1 + k0),
                                     (lv_t*)(&As[buf][ad1]), 16, 0, 0);
    __builtin_amdgcn_global_load_lds((const gv_t*)(Br0 + k0),
                                     (lv_t*)(&Bs[buf][ad0]), 16, 0, 0);
    __builtin_amdgcn_global_load_lds((const gv_t*)(Br1 + k0),
                                     (lv_t*)(&Bs[buf][ad1]), 16, 0, 0);
  };

  stage(0, 0);
  __syncthreads();
  int cur = 0;
  for (int k0 = 0; k0 < K; k0 += 32) {
    if (k0 + 32 < K) stage(cur ^ 1, k0 + 32);

    bf16x8 af[4], bfr[4];
    #pragma unroll
    for (int m = 0; m < 4; m++)
      af[m] = *(const bf16x8*)(&As[cur][aoff + m * 16 * 32]);
    #pragma unroll
    for (int n = 0; n < 4; n++)
      bfr[n] = *(const bf16x8*)(&Bs[cur][boff + n * 16 * 32]);
    #pragma unroll
    for (int m = 0; m < 4; m++)
      #pragma unroll
      for (int n = 0; n < 4; n++)
        acc[m][n] = __builtin_amdgcn_mfma_f32_16x16x32_bf16(af[m], bfr[n],
                                                            acc[m][n], 0, 0, 0);
    __syncthreads();
    cur ^= 1;
  }

  const int crow = (lane >> 4) * 4;
  const int ccol = lane & 15;
  #pragma unroll
  for (int m = 0; m < 4; m++)
    #pragma unroll
    for (int n = 0; n < 4; n++)
      #pragma unroll
      for (int j = 0; j < 4; j++) {
        int64_t row = bm * 128 + wm * 64 + m * 16 + crow + j;
        int64_t col = bn * 128 + wn * 64 + n * 16 + ccol;
        storeC(&C[row * ldc + col], acc[m][n][j]);
      }
}

// ---------------------------------------------------------------------------
// 256x256 8-phase GEMM (T2+T3+T4+T5). C[m,n] = sum_k A[m,k]*B[n,k].
// BK=64, 8 waves (2x4), per-wave 128x64 out = acc[8][4] frags of 16x16x32.
// LDS 128 KiB: As/Bs [2 dbuf][256][64] bf16, XOR-swizzle byte^=((row&7)<<4)
// (write side: pre-swizzled global source, linear global_load_lds dest).
// Per K-tile group of 4 phases (p1..p4, each: reads|stage, s_barrier,
// lgkmcnt(0), setprio1, 16 MFMA, setprio0, s_barrier); vmcnt(4) at group end.
//
// R4 change (m141 lesson): NO sched_barrier(0) inside phase bodies — the only
// load-bearing pins are (a) after the prologue barrier and (b) at the group
// tail, preventing next-group ds_reads from hoisting above the final barrier
// into the vmcnt(4)..barrier window (cross-wave staging race). All other
// orderings are guaranteed by register data-deps, side-effect ordering of
// {global_load_lds, s_barrier}, and the "memory"-clobber asm fences.
// ---------------------------------------------------------------------------
template <typename OUT_T>
__global__ __launch_bounds__(512, 2)
void gemm256(const bf16_t* __restrict__ A, const bf16_t* __restrict__ B,
             OUT_T* __restrict__ C0, OUT_T* __restrict__ C1,
             int K, int lda, int ldb, int ldc,
             int64_t b_batch_stride, int bm_per_batch,
             int64_t za_off, int64_t zb_off)
{
  __shared__ bf16_t As[2][256][64];
  __shared__ bf16_t Bs[2][256][64];

  const int tid  = threadIdx.x;
  const int wid  = tid >> 6;     // 0..7
  const int lane = tid & 63;
  const int wm = wid >> 2;       // 0..1 -> A half
  const int wn = wid & 3;        // 0..3 -> 64-col strip
  const int64_t bm = blockIdx.x;
  const int64_t bn = blockIdx.y;
  const int z = blockIdx.z;

  OUT_T* __restrict__ C = (z == 0) ? C0 : C1;
  const bf16_t* Ap = A + (int64_t)z * za_off;
  const bf16_t* Bp = B + (bm / bm_per_batch) * b_batch_stride
                       + (int64_t)z * zb_off;

  // staging (write side): pre-swizzled global source, linear LDS dest
  const int srow  = wid * 16 + (lane >> 3);
  const int sslot = (lane & 7) ^ (lane >> 3);
  const int64_t lda64 = lda, ldb64 = ldb;
  const bf16_t* Ag = Ap + (bm * 256 + srow) * lda64 + sslot * 8;
  const bf16_t* Bg = Bp + (bn * 256 + srow) * ldb64 + sslot * 8;

  auto stageA = [&](int buf, int t, int h) {
    const bf16_t* src = Ag + (int64_t)(h * 128) * lda64 + t * 64;
    char* dst = (char*)&As[buf][h * 128 + wid * 16][0];
    __builtin_amdgcn_global_load_lds((const gv_t*)src, (lv_t*)dst, 16, 0, 0);
    __builtin_amdgcn_global_load_lds((const gv_t*)(src + 8 * lda64),
                                     (lv_t*)(dst + 1024), 16, 0, 0);
  };
  auto stageB = [&](int buf, int t, int h) {
    const bf16_t* src = Bg + (int64_t)(h * 128) * ldb64 + t * 64;
    char* dst = (char*)&Bs[buf][h * 128 + wid * 16][0];
    __builtin_amdgcn_global_load_lds((const gv_t*)src, (lv_t*)dst, 16, 0, 0);
    __builtin_amdgcn_global_load_lds((const gv_t*)(src + 8 * ldb64),
                                     (lv_t*)(dst + 1024), 16, 0, 0);
  };

  // fragment read coords (swizzled)
  const int frow   = lane & 15;
  const int fcol16 = lane >> 4;               // 0..3
  const int xorv   = (lane & 7) << 4;
  const int ck0 = (fcol16 * 16) ^ xorv;
  const int ck1 = (64 + fcol16 * 16) ^ xorv;
  const int arowb = (wm * 128 + frow) * 128;
  const int browb = (wn * 64  + frow) * 128;

  f32x4 acc[8][4];
  #pragma unroll
  for (int m = 0; m < 8; m++)
    #pragma unroll
    for (int n = 0; n < 4; n++) acc[m][n] = f32x4{0.f, 0.f, 0.f, 0.f};

  const int NT = K >> 6;   // K-tiles of 64

  // prologue: T0 fully, T1.B halves; vmcnt(4) leaves T1.B in flight
  stageA(0, 0, 0); stageA(0, 0, 1);
  stageB(0, 0, 0); stageB(0, 0, 1);
  stageB(1, 1, 0); stageB(1, 1, 1);
  asm volatile("s_waitcnt vmcnt(4)" ::: "memory");
  __builtin_amdgcn_s_barrier();
  __builtin_amdgcn_sched_barrier(0);

  bf16x8 a[4][2], bb[4][2];

  for (int g = 0; g < NT; ++g) {
    const int buf = g & 1;
    const char* lA = (const char*)&As[buf][0][0];
    const char* lB = (const char*)&Bs[buf][0][0];

    // ======== phase 1: A m0-3, B n0-1; stage A(g+1).h0 -> other buf ========
    #pragma unroll
    for (int m = 0; m < 4; m++) {
      a[m][0] = *(const bf16x8*)(lA + arowb + m * 2048 + ck0);
      a[m][1] = *(const bf16x8*)(lA + arowb + m * 2048 + ck1);
    }
    #pragma unroll
    for (int n = 0; n < 2; n++) {
      bb[n][0] = *(const bf16x8*)(lB + browb + n * 2048 + ck0);
      bb[n][1] = *(const bf16x8*)(lB + browb + n * 2048 + ck1);
    }
    if (g + 1 < NT) stageA(buf ^ 1, g + 1, 0);
    __builtin_amdgcn_s_barrier();
    asm volatile("s_waitcnt lgkmcnt(0)" ::: "memory");
    __builtin_amdgcn_s_setprio(1);
    #pragma unroll
    for (int m = 0; m < 4; m++)
      #pragma unroll
      for (int n = 0; n < 2; n++)
        #pragma unroll
        for (int k = 0; k < 2; k++)
          acc[m][n] = __builtin_amdgcn_mfma_f32_16x16x32_bf16(a[m][k], bb[n][k],
                                                              acc[m][n], 0, 0, 0);
    __builtin_amdgcn_s_setprio(0);
    __builtin_amdgcn_s_barrier();

    // ======== phase 2: B n2-3; stage A(g+1).h1 ========
    #pragma unroll
    for (int n = 2; n < 4; n++) {
      bb[n][0] = *(const bf16x8*)(lB + browb + n * 2048 + ck0);
      bb[n][1] = *(const bf16x8*)(lB + browb + n * 2048 + ck1);
    }
    if (g + 1 < NT) stageA(buf ^ 1, g + 1, 1);
    __builtin_amdgcn_s_barrier();
    asm volatile("s_waitcnt lgkmcnt(0)" ::: "memory");
    __builtin_amdgcn_s_setprio(1);
    #pragma unroll
    for (int m = 0; m < 4; m++)
      #pragma unroll
      for (int n = 2; n < 4; n++)
        #pragma unroll
        for (int k = 0; k < 2; k++)
          acc[m][n] = __builtin_amdgcn_mfma_f32_16x16x32_bf16(a[m][k], bb[n][k],
                                                              acc[m][n], 0, 0, 0);
    __builtin_amdgcn_s_setprio(0);
    __builtin_amdgcn_s_barrier();

    // ======== phase 3: A m4-7; stage B(g+2).h0 -> this buf ========
    #pragma unroll
    for (int m = 0; m < 4; m++) {
      a[m][0] = *(const bf16x8*)(lA + arowb + (m + 4) * 2048 + ck0);
      a[m][1] = *(const bf16x8*)(lA + arowb + (m + 4) * 2048 + ck1);
    }
    if (g + 2 < NT) stageB(buf, g + 2, 0);
    __builtin_amdgcn_s_barrier();
    asm volatile("s_waitcnt lgkmcnt(0)" ::: "memory");
    __builtin_amdgcn_s_setprio(1);
    #pragma unroll
    for (int m = 0; m < 4; m++)
      #pragma unroll
      for (int n = 0; n < 2; n++)
        #pragma unroll
        for (int k = 0; k < 2; k++)
          acc[m + 4][n] = __builtin_amdgcn_mfma_f32_16x16x32_bf16(
              a[m][k], bb[n][k], acc[m + 4][n], 0, 0, 0);
    __builtin_amdgcn_s_setprio(0);
    __builtin_amdgcn_s_barrier();

    // ======== phase 4: no reads; stage B(g+2).h1; vmcnt(4) ========
    if (g + 2 < NT) stageB(buf, g + 2, 1);
    __builtin_amdgcn_s_barrier();
    asm volatile("s_waitcnt lgkmcnt(0)" ::: "memory");
    __builtin_amdgcn_s_setprio(1);
    #pragma unroll
    for (int m = 0; m < 4; m++)
      #pragma unroll
      for (int n = 2; n < 4; n++)
        #pragma unroll
        for (int k = 0; k < 2; k++)
          acc[m + 4][n] = __builtin_amdgcn_mfma_f32_16x16x32_bf16(
              a[m][k], bb[n][k], acc[m + 4][n], 0, 0, 0);
    __builtin_amdgcn_s_setprio(0);
    if (g + 2 < NT) {
      asm volatile("s_waitcnt vmcnt(4)" ::: "memory");  // next tile landed
    } else {
      asm volatile("s_waitcnt vmcnt(0)" ::: "memory");  // tail drain
    }
    __builtin_amdgcn_s_barrier();
    __builtin_amdgcn_sched_barrier(0);   // pin: next-group reads stay below
  }

  // epilogue: C/D layout col=lane&15, row=(lane>>4)*4+j
  const int crow = (lane >> 4) * 4;
  const int ccol = lane & 15;
  #pragma unroll
  for (int m = 0; m < 8; m++)
    #pragma unroll
    for (int n = 0; n < 4; n++)
      #pragma unroll
      for (int j = 0; j < 4; j++) {
        int64_t row = bm * 256 + wm * 128 + m * 16 + crow + j;
        int64_t col = bn * 256 + wn * 64 + n * 16 + ccol;
        storeC(&C[row * (int64_t)ldc + col], acc[m][n][j]);
      }
}

// ---------------------------------------------------------------------------
// Row softmax IN PLACE: fp16 raw scores [rows x 4096] -> normalized bf16 P.
// ---------------------------------------------------------------------------
__global__ __launch_bounds__(256)
void softmax_rows(__half* __restrict__ SP)
{
  const int64_t row = blockIdx.x;
  __half* s = SP + row * 4096;
  bf16_t* p = (bf16_t*)s;
  const int tid = threadIdx.x;
  const float scale = 0.03125f;  // 1/sqrt(1024)

  float v[16];
  float vmax = -3.4e38f;
  #pragma unroll
  for (int i = 0; i < 4; i++) {
    uint2 raw = *(const uint2*)(s + i * 1024 + tid * 4);
    __half2 h01 = __builtin_bit_cast(__half2, raw.x);
    __half2 h23 = __builtin_bit_cast(__half2, raw.y);
    float2 f01 = __half22float2(h01);
    float2 f23 = __half22float2(h23);
    v[i * 4 + 0] = f01.x * scale;
    v[i * 4 + 1] = f01.y * scale;
    v[i * 4 + 2] = f23.x * scale;
    v[i * 4 + 3] = f23.y * scale;
    vmax = fmaxf(vmax, fmaxf(fmaxf(v[i*4+0], v[i*4+1]),
                             fmaxf(v[i*4+2], v[i*4+3])));
  }
  #pragma unroll
  for (int o = 32; o > 0; o >>= 1) vmax = fmaxf(vmax, __shfl_xor(vmax, o));
  __shared__ float redm[4];
  __shared__ float reds[4];
  if ((tid & 63) == 0) redm[tid >> 6] = vmax;
  __syncthreads();
  vmax = fmaxf(fmaxf(redm[0], redm[1]), fmaxf(redm[2], redm[3]));

  float lsum = 0.f;
  #pragma unroll
  for (int i = 0; i < 16; i++) {
    v[i] = __expf(v[i] - vmax);
    lsum += v[i];
  }
  #pragma unroll
  for (int o = 32; o > 0; o >>= 1) lsum += __shfl_xor(lsum, o);
  if ((tid & 63) == 0) reds[tid >> 6] = lsum;
  __syncthreads();
  lsum = (reds[0] + reds[1]) + (reds[2] + reds[3]);
  const float inv = 1.0f / lsum;

  #pragma unroll
  for (int i = 0; i < 4; i++) {
    uint32_t lo = ((uint32_t)f2bf_bits(v[i*4+1] * inv) << 16) | f2bf_bits(v[i*4+0] * inv);
    uint32_t hi = ((uint32_t)f2bf_bits(v[i*4+3] * inv) << 16) | f2bf_bits(v[i*4+2] * inv);
    *(uint2*)(p + i * 1024 + tid * 4) = make_uint2(lo, hi);
  }
}

// ---------------------------------------------------------------------------
// out[i] += partial[i]  (split-K reduce), float4 vectorized
// ---------------------------------------------------------------------------
__global__ __launch_bounds__(256)
void addk_f4(float4* __restrict__ o, const float4* __restrict__ a, int64_t n4)
{
  for (int64_t i = (int64_t)blockIdx.x * blockDim.x + threadIdx.x; i < n4;
       i += (int64_t)gridDim.x * blockDim.x) {
    float4 x = o[i];
    float4 y = a[i];
    x.x += y.x; x.y += y.y; x.z += y.z; x.w += y.w;
    o[i] = x;
  }
}

// ---------------------------------------------------------------------------
// ws layout (112 MiB):
//   [0,   64M): S/P fp16->bf16 [8192 x 4096]
//               overlapped early: xb [0,16M), wqkb [16M,20M), wvb [20M,22M)
//   [64M, 96M): qk bf16 [8192 x 2048] (Q|K); reused as PV split-K partial (f32)
//   [96M,112M): vt bf16 [1024 x 8192]
// ---------------------------------------------------------------------------
extern "C" void kernel_launch(void* const* d_in, const int* in_sizes, int n_in,
                              void* d_out, int out_size, void* d_ws, size_t ws_size,
                              hipStream_t stream) {
  const float* x  = (const float*)d_in[0];
  const float* wq = (const float*)d_in[1];
  const float* wk = (const float*)d_in[2];
  const float* wv = (const float*)d_in[3];
  float* out = (float*)d_out;

  char* ws = (char*)d_ws;
  bf16_t* xb   = (bf16_t*)ws;
  bf16_t* wqkb = (bf16_t*)(ws + (16LL << 20));
  bf16_t* wvb  = (bf16_t*)(ws + (20LL << 20));
  __half* S    = (__half*)ws;
  bf16_t* qk   = (bf16_t*)(ws + (64LL << 20));
  float*  pk   = (float*)(ws + (64LL << 20));   // PV split-K partial (32 MiB)
  bf16_t* vt   = (bf16_t*)(ws + (96LL << 20));

  const int NO_BATCH = 1 << 30;

  convert_all<<<2048, 256, 0, stream>>>(x, wq, wk, wv, xb, wqkb, wvb);

  // qk[8192 x 2048] = xb * wqkb^T
  gemm256<bf16_t><<<dim3(32, 8, 1), 512, 0, stream>>>(
      xb, wqkb, qk, qk, 1024, 1024, 1024, 2048, 0, NO_BATCH, 0, 0);

  // vt[1024 x 8192] = wvb * xb^T
  gemm_bt<bf16_t><<<dim3(8, 64), 256, 0, stream>>>(
      wvb, xb, vt, 1024, 1024, 1024, 8192, 0, NO_BATCH);

  // S[8192 x 4096] = Q * K_b^T (raw fp16), batch b = bm/16
  gemm256<__half><<<dim3(32, 16, 1), 512, 0, stream>>>(
      qk, qk + 1024, S, S, 1024, 2048, 2048, 4096, 4096LL * 2048, 16, 0, 0);

  softmax_rows<<<8192, 256, 0, stream>>>(S);

  // out[8192 x 1024] = P * V_b^T, split-K (z: k-chunk of 2048), batch = bm/16
  gemm256<float><<<dim3(32, 4, 2), 512, 0, stream>>>(
      (const bf16_t*)S, vt, out, pk, 2048, 4096, 8192, 1024,
      4096, 16, 2048, 2048);

  addk_f4<<<2048, 256, 0, stream>>>((float4*)out, (const float4*)pk,
                                    8192LL * 1024 / 4);
}

// Round 5
// 248.970 us; speedup vs baseline: 1.0074x; 1.0074x over previous
//
#include <hip/hip_runtime.h>
#include <hip/hip_bf16.h>
#include <hip/hip_fp16.h>
#include <stdint.h>

typedef __bf16 bf16_t;
typedef __bf16 bf16x8 __attribute__((ext_vector_type(8)));
typedef float f32x4 __attribute__((ext_vector_type(4)));

typedef __attribute__((address_space(1))) void gv_t;
typedef __attribute__((address_space(3))) void lv_t;

__device__ inline unsigned short f2bf_bits(float f) {
  uint32_t u = __float_as_uint(f);
  u += 0x7FFFu + ((u >> 16) & 1u);   // RNE
  return (unsigned short)(u >> 16);
}
__device__ inline bf16_t f2bf(float f) {
  unsigned short h = f2bf_bits(f);
  return __builtin_bit_cast(bf16_t, h);
}

__device__ inline void storeC(float* p, float v) { *p = v; }
__device__ inline void storeC(bf16_t* p, float v) { *p = f2bf(v); }
__device__ inline void storeC(__half* p, float v) { *p = __float2half(v); }

// ---------------------------------------------------------------------------
// fp32 -> bf16 conversion for x, Wq, Wk (packed together), Wv
// ---------------------------------------------------------------------------
__global__ __launch_bounds__(256)
void convert_all(const float* __restrict__ x, const float* __restrict__ wq,
                 const float* __restrict__ wk, const float* __restrict__ wv,
                 bf16_t* __restrict__ xb, bf16_t* __restrict__ wqkb,
                 bf16_t* __restrict__ wvb)
{
  const int64_t NX = 8192LL * 1024, NW = 1024LL * 1024;
  const int64_t total4 = (NX + 3 * NW) >> 2;
  for (int64_t i = (int64_t)blockIdx.x * blockDim.x + threadIdx.x; i < total4;
       i += (int64_t)gridDim.x * blockDim.x) {
    int64_t e = i << 2;
    const float* src; bf16_t* dst; int64_t off;
    if (e < NX)               { src = x;  dst = xb;         off = e; }
    else if (e < NX + NW)     { src = wq; dst = wqkb;       off = e - NX; }
    else if (e < NX + 2 * NW) { src = wk; dst = wqkb + NW;  off = e - NX - NW; }
    else                      { src = wv; dst = wvb;        off = e - NX - 2 * NW; }
    float4 f = *(const float4*)(src + off);
    uint32_t lo = ((uint32_t)f2bf_bits(f.y) << 16) | f2bf_bits(f.x);
    uint32_t hi = ((uint32_t)f2bf_bits(f.w) << 16) | f2bf_bits(f.z);
    *(uint2*)(dst + off) = make_uint2(lo, hi);
  }
}

// ---------------------------------------------------------------------------
// Legacy 128x128 2-phase gemm (kept for the small Vt projection only).
// ---------------------------------------------------------------------------
template <typename OUT_T>
__global__ __launch_bounds__(256)
void gemm_bt(const bf16_t* __restrict__ A, const bf16_t* __restrict__ B,
             OUT_T* __restrict__ C, int K, int lda, int ldb, int ldc,
             int64_t b_batch_stride, int bm_per_batch)
{
  __shared__ bf16_t As[2][128 * 32];
  __shared__ bf16_t Bs[2][128 * 32];
  const int tid  = threadIdx.x;
  const int wid  = tid >> 6;
  const int lane = tid & 63;
  const int wm = wid >> 1, wn = wid & 1;
  const int64_t bm = blockIdx.x;
  const int64_t bn = blockIdx.y;

  const bf16_t* Bb = B + (bm / bm_per_batch) * b_batch_stride;

  const int c0row = (wid * 2 + 0) * 16 + (lane >> 2);
  const int c1row = (wid * 2 + 1) * 16 + (lane >> 2);
  const int scol  = (lane & 3) * 8;

  const bf16_t* Ar0 = A  + (bm * 128 + c0row) * lda + scol;
  const bf16_t* Ar1 = A  + (bm * 128 + c1row) * lda + scol;
  const bf16_t* Br0 = Bb + (bn * 128 + c0row) * ldb + scol;
  const bf16_t* Br1 = Bb + (bn * 128 + c1row) * ldb + scol;

  const int ad0 = (wid * 2 + 0) * 512;
  const int ad1 = (wid * 2 + 1) * 512;

  const int frow = lane & 15;
  const int fk   = (lane >> 4) * 8;
  const int aoff = (wm * 64 + frow) * 32 + fk;
  const int boff = (wn * 64 + frow) * 32 + fk;

  f32x4 acc[4][4];
  #pragma unroll
  for (int m = 0; m < 4; m++)
    #pragma unroll
    for (int n = 0; n < 4; n++) acc[m][n] = f32x4{0.f, 0.f, 0.f, 0.f};

  auto stage = [&](int buf, int k0) {
    __builtin_amdgcn_global_load_lds((const gv_t*)(Ar0 + k0),
                                     (lv_t*)(&As[buf][ad0]), 16, 0, 0);
    __builtin_amdgcn_global_load_lds((const gv_t*)(Ar1 + k0),
                                     (lv_t*)(&As[buf][ad1]), 16, 0, 0);
    __builtin_amdgcn_global_load_lds((const gv_t*)(Br0 + k0),
                                     (lv_t*)(&Bs[buf][ad0]), 16, 0, 0);
    __builtin_amdgcn_global_load_lds((const gv_t*)(Br1 + k0),
                                     (lv_t*)(&Bs[buf][ad1]), 16, 0, 0);
  };

  stage(0, 0);
  __syncthreads();
  int cur = 0;
  for (int k0 = 0; k0 < K; k0 += 32) {
    if (k0 + 32 < K) stage(cur ^ 1, k0 + 32);

    bf16x8 af[4], bfr[4];
    #pragma unroll
    for (int m = 0; m < 4; m++)
      af[m] = *(const bf16x8*)(&As[cur][aoff + m * 16 * 32]);
    #pragma unroll
    for (int n = 0; n < 4; n++)
      bfr[n] = *(const bf16x8*)(&Bs[cur][boff + n * 16 * 32]);
    #pragma unroll
    for (int m = 0; m < 4; m++)
      #pragma unroll
      for (int n = 0; n < 4; n++)
        acc[m][n] = __builtin_amdgcn_mfma_f32_16x16x32_bf16(af[m], bfr[n],
                                                            acc[m][n], 0, 0, 0);
    __syncthreads();
    cur ^= 1;
  }

  const int crow = (lane >> 4) * 4;
  const int ccol = lane & 15;
  #pragma unroll
  for (int m = 0; m < 4; m++)
    #pragma unroll
    for (int n = 0; n < 4; n++)
      #pragma unroll
      for (int j = 0; j < 4; j++) {
        int64_t row = bm * 128 + wm * 64 + m * 16 + crow + j;
        int64_t col = bn * 128 + wn * 64 + n * 16 + ccol;
        storeC(&C[row * ldc + col], acc[m][n][j]);
      }
}

// ---------------------------------------------------------------------------
// 256x256 8-phase GEMM (T2+T3+T4+T5). C[m,n] = sum_k A[m,k]*B[n,k].
// BK=64, 8 waves (2x4), per-wave 128x64 out = acc[8][4] frags of 16x16x32.
// LDS 128 KiB: As/Bs [2 dbuf][256][64] bf16, XOR-swizzle byte^=((row&7)<<4)
// (write side: pre-swizzled global source, linear global_load_lds dest).
//
// R5 change (single variable vs R4): the per-phase
// `asm volatile("s_waitcnt lgkmcnt(0)")` full-drains are DELETED. The
// compiler's waitcnt pass tracks the ds_read->register->MFMA deps and emits
// minimal counted lgkmcnt waits, so MFMAs start as soon as their own
// fragments land while the remaining reads drain underneath (intra-phase
// LDS/MFMA overlap). Cross-wave WAR safety is preserved: every fragment's
// first use is in its read phase, so its reads complete before that wave
// passes the phase's closing barrier, and every staging overwrite happens
// >=1 barrier later (same placement as R4).
// ---------------------------------------------------------------------------
template <typename OUT_T>
__global__ __launch_bounds__(512, 2)
void gemm256(const bf16_t* __restrict__ A, const bf16_t* __restrict__ B,
             OUT_T* __restrict__ C0, OUT_T* __restrict__ C1,
             int K, int lda, int ldb, int ldc,
             int64_t b_batch_stride, int bm_per_batch,
             int64_t za_off, int64_t zb_off)
{
  __shared__ bf16_t As[2][256][64];
  __shared__ bf16_t Bs[2][256][64];

  const int tid  = threadIdx.x;
  const int wid  = tid >> 6;     // 0..7
  const int lane = tid & 63;
  const int wm = wid >> 2;       // 0..1 -> A half
  const int wn = wid & 3;        // 0..3 -> 64-col strip
  const int64_t bm = blockIdx.x;
  const int64_t bn = blockIdx.y;
  const int z = blockIdx.z;

  OUT_T* __restrict__ C = (z == 0) ? C0 : C1;
  const bf16_t* Ap = A + (int64_t)z * za_off;
  const bf16_t* Bp = B + (bm / bm_per_batch) * b_batch_stride
                       + (int64_t)z * zb_off;

  // staging (write side): pre-swizzled global source, linear LDS dest
  const int srow  = wid * 16 + (lane >> 3);
  const int sslot = (lane & 7) ^ (lane >> 3);
  const int64_t lda64 = lda, ldb64 = ldb;
  const bf16_t* Ag = Ap + (bm * 256 + srow) * lda64 + sslot * 8;
  const bf16_t* Bg = Bp + (bn * 256 + srow) * ldb64 + sslot * 8;

  auto stageA = [&](int buf, int t, int h) {
    const bf16_t* src = Ag + (int64_t)(h * 128) * lda64 + t * 64;
    char* dst = (char*)&As[buf][h * 128 + wid * 16][0];
    __builtin_amdgcn_global_load_lds((const gv_t*)src, (lv_t*)dst, 16, 0, 0);
    __builtin_amdgcn_global_load_lds((const gv_t*)(src + 8 * lda64),
                                     (lv_t*)(dst + 1024), 16, 0, 0);
  };
  auto stageB = [&](int buf, int t, int h) {
    const bf16_t* src = Bg + (int64_t)(h * 128) * ldb64 + t * 64;
    char* dst = (char*)&Bs[buf][h * 128 + wid * 16][0];
    __builtin_amdgcn_global_load_lds((const gv_t*)src, (lv_t*)dst, 16, 0, 0);
    __builtin_amdgcn_global_load_lds((const gv_t*)(src + 8 * ldb64),
                                     (lv_t*)(dst + 1024), 16, 0, 0);
  };

  // fragment read coords (swizzled)
  const int frow   = lane & 15;
  const int fcol16 = lane >> 4;               // 0..3
  const int xorv   = (lane & 7) << 4;
  const int ck0 = (fcol16 * 16) ^ xorv;
  const int ck1 = (64 + fcol16 * 16) ^ xorv;
  const int arowb = (wm * 128 + frow) * 128;
  const int browb = (wn * 64  + frow) * 128;

  f32x4 acc[8][4];
  #pragma unroll
  for (int m = 0; m < 8; m++)
    #pragma unroll
    for (int n = 0; n < 4; n++) acc[m][n] = f32x4{0.f, 0.f, 0.f, 0.f};

  const int NT = K >> 6;   // K-tiles of 64

  // prologue: T0 fully, T1.B halves; vmcnt(4) leaves T1.B in flight
  stageA(0, 0, 0); stageA(0, 0, 1);
  stageB(0, 0, 0); stageB(0, 0, 1);
  stageB(1, 1, 0); stageB(1, 1, 1);
  asm volatile("s_waitcnt vmcnt(4)" ::: "memory");
  __builtin_amdgcn_s_barrier();
  __builtin_amdgcn_sched_barrier(0);

  bf16x8 a[4][2], bb[4][2];

  for (int g = 0; g < NT; ++g) {
    const int buf = g & 1;
    const char* lA = (const char*)&As[buf][0][0];
    const char* lB = (const char*)&Bs[buf][0][0];

    // ======== phase 1: A m0-3, B n0-1; stage A(g+1).h0 -> other buf ========
    #pragma unroll
    for (int m = 0; m < 4; m++) {
      a[m][0] = *(const bf16x8*)(lA + arowb + m * 2048 + ck0);
      a[m][1] = *(const bf16x8*)(lA + arowb + m * 2048 + ck1);
    }
    #pragma unroll
    for (int n = 0; n < 2; n++) {
      bb[n][0] = *(const bf16x8*)(lB + browb + n * 2048 + ck0);
      bb[n][1] = *(const bf16x8*)(lB + browb + n * 2048 + ck1);
    }
    if (g + 1 < NT) stageA(buf ^ 1, g + 1, 0);
    __builtin_amdgcn_s_barrier();
    __builtin_amdgcn_s_setprio(1);
    #pragma unroll
    for (int m = 0; m < 4; m++)
      #pragma unroll
      for (int n = 0; n < 2; n++)
        #pragma unroll
        for (int k = 0; k < 2; k++)
          acc[m][n] = __builtin_amdgcn_mfma_f32_16x16x32_bf16(a[m][k], bb[n][k],
                                                              acc[m][n], 0, 0, 0);
    __builtin_amdgcn_s_setprio(0);
    __builtin_amdgcn_s_barrier();

    // ======== phase 2: B n2-3; stage A(g+1).h1 ========
    #pragma unroll
    for (int n = 2; n < 4; n++) {
      bb[n][0] = *(const bf16x8*)(lB + browb + n * 2048 + ck0);
      bb[n][1] = *(const bf16x8*)(lB + browb + n * 2048 + ck1);
    }
    if (g + 1 < NT) stageA(buf ^ 1, g + 1, 1);
    __builtin_amdgcn_s_barrier();
    __builtin_amdgcn_s_setprio(1);
    #pragma unroll
    for (int m = 0; m < 4; m++)
      #pragma unroll
      for (int n = 2; n < 4; n++)
        #pragma unroll
        for (int k = 0; k < 2; k++)
          acc[m][n] = __builtin_amdgcn_mfma_f32_16x16x32_bf16(a[m][k], bb[n][k],
                                                              acc[m][n], 0, 0, 0);
    __builtin_amdgcn_s_setprio(0);
    __builtin_amdgcn_s_barrier();

    // ======== phase 3: A m4-7; stage B(g+2).h0 -> this buf ========
    #pragma unroll
    for (int m = 0; m < 4; m++) {
      a[m][0] = *(const bf16x8*)(lA + arowb + (m + 4) * 2048 + ck0);
      a[m][1] = *(const bf16x8*)(lA + arowb + (m + 4) * 2048 + ck1);
    }
    if (g + 2 < NT) stageB(buf, g + 2, 0);
    __builtin_amdgcn_s_barrier();
    __builtin_amdgcn_s_setprio(1);
    #pragma unroll
    for (int m = 0; m < 4; m++)
      #pragma unroll
      for (int n = 0; n < 2; n++)
        #pragma unroll
        for (int k = 0; k < 2; k++)
          acc[m + 4][n] = __builtin_amdgcn_mfma_f32_16x16x32_bf16(
              a[m][k], bb[n][k], acc[m + 4][n], 0, 0, 0);
    __builtin_amdgcn_s_setprio(0);
    __builtin_amdgcn_s_barrier();

    // ======== phase 4: no reads; stage B(g+2).h1; vmcnt(4) ========
    if (g + 2 < NT) stageB(buf, g + 2, 1);
    __builtin_amdgcn_s_barrier();
    __builtin_amdgcn_s_setprio(1);
    #pragma unroll
    for (int m = 0; m < 4; m++)
      #pragma unroll
      for (int n = 2; n < 4; n++)
        #pragma unroll
        for (int k = 0; k < 2; k++)
          acc[m + 4][n] = __builtin_amdgcn_mfma_f32_16x16x32_bf16(
              a[m][k], bb[n][k], acc[m + 4][n], 0, 0, 0);
    __builtin_amdgcn_s_setprio(0);
    if (g + 2 < NT) {
      asm volatile("s_waitcnt vmcnt(4)" ::: "memory");  // next tile landed
    } else {
      asm volatile("s_waitcnt vmcnt(0)" ::: "memory");  // tail drain
    }
    __builtin_amdgcn_s_barrier();
    __builtin_amdgcn_sched_barrier(0);   // pin: next-group reads stay below
  }

  // epilogue: C/D layout col=lane&15, row=(lane>>4)*4+j
  const int crow = (lane >> 4) * 4;
  const int ccol = lane & 15;
  #pragma unroll
  for (int m = 0; m < 8; m++)
    #pragma unroll
    for (int n = 0; n < 4; n++)
      #pragma unroll
      for (int j = 0; j < 4; j++) {
        int64_t row = bm * 256 + wm * 128 + m * 16 + crow + j;
        int64_t col = bn * 256 + wn * 64 + n * 16 + ccol;
        storeC(&C[row * (int64_t)ldc + col], acc[m][n][j]);
      }
}

// ---------------------------------------------------------------------------
// Row softmax IN PLACE: fp16 raw scores [rows x 4096] -> normalized bf16 P.
// ---------------------------------------------------------------------------
__global__ __launch_bounds__(256)
void softmax_rows(__half* __restrict__ SP)
{
  const int64_t row = blockIdx.x;
  __half* s = SP + row * 4096;
  bf16_t* p = (bf16_t*)s;
  const int tid = threadIdx.x;
  const float scale = 0.03125f;  // 1/sqrt(1024)

  float v[16];
  float vmax = -3.4e38f;
  #pragma unroll
  for (int i = 0; i < 4; i++) {
    uint2 raw = *(const uint2*)(s + i * 1024 + tid * 4);
    __half2 h01 = __builtin_bit_cast(__half2, raw.x);
    __half2 h23 = __builtin_bit_cast(__half2, raw.y);
    float2 f01 = __half22float2(h01);
    float2 f23 = __half22float2(h23);
    v[i * 4 + 0] = f01.x * scale;
    v[i * 4 + 1] = f01.y * scale;
    v[i * 4 + 2] = f23.x * scale;
    v[i * 4 + 3] = f23.y * scale;
    vmax = fmaxf(vmax, fmaxf(fmaxf(v[i*4+0], v[i*4+1]),
                             fmaxf(v[i*4+2], v[i*4+3])));
  }
  #pragma unroll
  for (int o = 32; o > 0; o >>= 1) vmax = fmaxf(vmax, __shfl_xor(vmax, o));
  __shared__ float redm[4];
  __shared__ float reds[4];
  if ((tid & 63) == 0) redm[tid >> 6] = vmax;
  __syncthreads();
  vmax = fmaxf(fmaxf(redm[0], redm[1]), fmaxf(redm[2], redm[3]));

  float lsum = 0.f;
  #pragma unroll
  for (int i = 0; i < 16; i++) {
    v[i] = __expf(v[i] - vmax);
    lsum += v[i];
  }
  #pragma unroll
  for (int o = 32; o > 0; o >>= 1) lsum += __shfl_xor(lsum, o);
  if ((tid & 63) == 0) reds[tid >> 6] = lsum;
  __syncthreads();
  lsum = (reds[0] + reds[1]) + (reds[2] + reds[3]);
  const float inv = 1.0f / lsum;

  #pragma unroll
  for (int i = 0; i < 4; i++) {
    uint32_t lo = ((uint32_t)f2bf_bits(v[i*4+1] * inv) << 16) | f2bf_bits(v[i*4+0] * inv);
    uint32_t hi = ((uint32_t)f2bf_bits(v[i*4+3] * inv) << 16) | f2bf_bits(v[i*4+2] * inv);
    *(uint2*)(p + i * 1024 + tid * 4) = make_uint2(lo, hi);
  }
}

// ---------------------------------------------------------------------------
// out[i] += partial[i]  (split-K reduce), float4 vectorized
// ---------------------------------------------------------------------------
__global__ __launch_bounds__(256)
void addk_f4(float4* __restrict__ o, const float4* __restrict__ a, int64_t n4)
{
  for (int64_t i = (int64_t)blockIdx.x * blockDim.x + threadIdx.x; i < n4;
       i += (int64_t)gridDim.x * blockDim.x) {
    float4 x = o[i];
    float4 y = a[i];
    x.x += y.x; x.y += y.y; x.z += y.z; x.w += y.w;
    o[i] = x;
  }
}

// ---------------------------------------------------------------------------
// ws layout (112 MiB):
//   [0,   64M): S/P fp16->bf16 [8192 x 4096]
//               overlapped early: xb [0,16M), wqkb [16M,20M), wvb [20M,22M)
//   [64M, 96M): qk bf16 [8192 x 2048] (Q|K); reused as PV split-K partial (f32)
//   [96M,112M): vt bf16 [1024 x 8192]
// ---------------------------------------------------------------------------
extern "C" void kernel_launch(void* const* d_in, const int* in_sizes, int n_in,
                              void* d_out, int out_size, void* d_ws, size_t ws_size,
                              hipStream_t stream) {
  const float* x  = (const float*)d_in[0];
  const float* wq = (const float*)d_in[1];
  const float* wk = (const float*)d_in[2];
  const float* wv = (const float*)d_in[3];
  float* out = (float*)d_out;

  char* ws = (char*)d_ws;
  bf16_t* xb   = (bf16_t*)ws;
  bf16_t* wqkb = (bf16_t*)(ws + (16LL << 20));
  bf16_t* wvb  = (bf16_t*)(ws + (20LL << 20));
  __half* S    = (__half*)ws;
  bf16_t* qk   = (bf16_t*)(ws + (64LL << 20));
  float*  pk   = (float*)(ws + (64LL << 20));   // PV split-K partial (32 MiB)
  bf16_t* vt   = (bf16_t*)(ws + (96LL << 20));

  const int NO_BATCH = 1 << 30;

  convert_all<<<2048, 256, 0, stream>>>(x, wq, wk, wv, xb, wqkb, wvb);

  // qk[8192 x 2048] = xb * wqkb^T
  gemm256<bf16_t><<<dim3(32, 8, 1), 512, 0, stream>>>(
      xb, wqkb, qk, qk, 1024, 1024, 1024, 2048, 0, NO_BATCH, 0, 0);

  // vt[1024 x 8192] = wvb * xb^T
  gemm_bt<bf16_t><<<dim3(8, 64), 256, 0, stream>>>(
      wvb, xb, vt, 1024, 1024, 1024, 8192, 0, NO_BATCH);

  // S[8192 x 4096] = Q * K_b^T (raw fp16), batch b = bm/16
  gemm256<__half><<<dim3(32, 16, 1), 512, 0, stream>>>(
      qk, qk + 1024, S, S, 1024, 2048, 2048, 4096, 4096LL * 2048, 16, 0, 0);

  softmax_rows<<<8192, 256, 0, stream>>>(S);

  // out[8192 x 1024] = P * V_b^T, split-K (z: k-chunk of 2048), batch = bm/16
  gemm256<float><<<dim3(32, 4, 2), 512, 0, stream>>>(
      (const bf16_t*)S, vt, out, pk, 2048, 4096, 8192, 1024,
      4096, 16, 2048, 2048);

  addk_f4<<<2048, 256, 0, stream>>>((float4*)out, (const float4*)pk,
                                    8192LL * 1024 / 4);
}

// Round 7
// 247.317 us; speedup vs baseline: 1.0142x; 1.0067x over previous
//
#include <hip/hip_runtime.h>
#include <hip/hip_bf16.h>
#include <hip/hip_fp16.h>
#include <stdint.h>

typedef __bf16 bf16_t;
typedef __bf16 bf16x8 __attribute__((ext_vector_type(8)));
typedef float f32x4 __attribute__((ext_vector_type(4)));

typedef __attribute__((address_space(1))) void gv_t;
typedef __attribute__((address_space(3))) void lv_t;

__device__ inline unsigned short f2bf_bits(float f) {
  uint32_t u = __float_as_uint(f);
  u += 0x7FFFu + ((u >> 16) & 1u);   // RNE
  return (unsigned short)(u >> 16);
}
__device__ inline bf16_t f2bf(float f) {
  unsigned short h = f2bf_bits(f);
  return __builtin_bit_cast(bf16_t, h);
}

__device__ inline void storeC(float* p, float v) { *p = v; }
__device__ inline void storeC(bf16_t* p, float v) { *p = f2bf(v); }
__device__ inline void storeC(__half* p, float v) { *p = __float2half(v); }

// ---------------------------------------------------------------------------
// fp32 -> bf16 conversion for x, Wq, Wk (packed together), Wv
// ---------------------------------------------------------------------------
__global__ __launch_bounds__(256)
void convert_all(const float* __restrict__ x, const float* __restrict__ wq,
                 const float* __restrict__ wk, const float* __restrict__ wv,
                 bf16_t* __restrict__ xb, bf16_t* __restrict__ wqkb,
                 bf16_t* __restrict__ wvb)
{
  const int64_t NX = 8192LL * 1024, NW = 1024LL * 1024;
  const int64_t total4 = (NX + 3 * NW) >> 2;
  for (int64_t i = (int64_t)blockIdx.x * blockDim.x + threadIdx.x; i < total4;
       i += (int64_t)gridDim.x * blockDim.x) {
    int64_t e = i << 2;
    const float* src; bf16_t* dst; int64_t off;
    if (e < NX)               { src = x;  dst = xb;         off = e; }
    else if (e < NX + NW)     { src = wq; dst = wqkb;       off = e - NX; }
    else if (e < NX + 2 * NW) { src = wk; dst = wqkb + NW;  off = e - NX - NW; }
    else                      { src = wv; dst = wvb;        off = e - NX - 2 * NW; }
    float4 f = *(const float4*)(src + off);
    uint32_t lo = ((uint32_t)f2bf_bits(f.y) << 16) | f2bf_bits(f.x);
    uint32_t hi = ((uint32_t)f2bf_bits(f.w) << 16) | f2bf_bits(f.z);
    *(uint2*)(dst + off) = make_uint2(lo, hi);
  }
}

// ---------------------------------------------------------------------------
// Legacy 128x128 2-phase gemm (kept for the small Vt projection only).
// ---------------------------------------------------------------------------
template <typename OUT_T>
__global__ __launch_bounds__(256)
void gemm_bt(const bf16_t* __restrict__ A, const bf16_t* __restrict__ B,
             OUT_T* __restrict__ C, int K, int lda, int ldb, int ldc,
             int64_t b_batch_stride, int bm_per_batch)
{
  __shared__ bf16_t As[2][128 * 32];
  __shared__ bf16_t Bs[2][128 * 32];
  const int tid  = threadIdx.x;
  const int wid  = tid >> 6;
  const int lane = tid & 63;
  const int wm = wid >> 1, wn = wid & 1;
  const int64_t bm = blockIdx.x;
  const int64_t bn = blockIdx.y;

  const bf16_t* Bb = B + (bm / bm_per_batch) * b_batch_stride;

  const int c0row = (wid * 2 + 0) * 16 + (lane >> 2);
  const int c1row = (wid * 2 + 1) * 16 + (lane >> 2);
  const int scol  = (lane & 3) * 8;

  const bf16_t* Ar0 = A  + (bm * 128 + c0row) * lda + scol;
  const bf16_t* Ar1 = A  + (bm * 128 + c1row) * lda + scol;
  const bf16_t* Br0 = Bb + (bn * 128 + c0row) * ldb + scol;
  const bf16_t* Br1 = Bb + (bn * 128 + c1row) * ldb + scol;

  const int ad0 = (wid * 2 + 0) * 512;
  const int ad1 = (wid * 2 + 1) * 512;

  const int frow = lane & 15;
  const int fk   = (lane >> 4) * 8;
  const int aoff = (wm * 64 + frow) * 32 + fk;
  const int boff = (wn * 64 + frow) * 32 + fk;

  f32x4 acc[4][4];
  #pragma unroll
  for (int m = 0; m < 4; m++)
    #pragma unroll
    for (int n = 0; n < 4; n++) acc[m][n] = f32x4{0.f, 0.f, 0.f, 0.f};

  auto stage = [&](int buf, int k0) {
    __builtin_amdgcn_global_load_lds((const gv_t*)(Ar0 + k0),
                                     (lv_t*)(&As[buf][ad0]), 16, 0, 0);
    __builtin_amdgcn_global_load_lds((const gv_t*)(Ar1 + k0),
                                     (lv_t*)(&As[buf][ad1]), 16, 0, 0);
    __builtin_amdgcn_global_load_lds((const gv_t*)(Br0 + k0),
                                     (lv_t*)(&Bs[buf][ad0]), 16, 0, 0);
    __builtin_amdgcn_global_load_lds((const gv_t*)(Br1 + k0),
                                     (lv_t*)(&Bs[buf][ad1]), 16, 0, 0);
  };

  stage(0, 0);
  __syncthreads();
  int cur = 0;
  for (int k0 = 0; k0 < K; k0 += 32) {
    if (k0 + 32 < K) stage(cur ^ 1, k0 + 32);

    bf16x8 af[4], bfr[4];
    #pragma unroll
    for (int m = 0; m < 4; m++)
      af[m] = *(const bf16x8*)(&As[cur][aoff + m * 16 * 32]);
    #pragma unroll
    for (int n = 0; n < 4; n++)
      bfr[n] = *(const bf16x8*)(&Bs[cur][boff + n * 16 * 32]);
    #pragma unroll
    for (int m = 0; m < 4; m++)
      #pragma unroll
      for (int n = 0; n < 4; n++)
        acc[m][n] = __builtin_amdgcn_mfma_f32_16x16x32_bf16(af[m], bfr[n],
                                                            acc[m][n], 0, 0, 0);
    __syncthreads();
    cur ^= 1;
  }

  const int crow = (lane >> 4) * 4;
  const int ccol = lane & 15;
  #pragma unroll
  for (int m = 0; m < 4; m++)
    #pragma unroll
    for (int n = 0; n < 4; n++)
      #pragma unroll
      for (int j = 0; j < 4; j++) {
        int64_t row = bm * 128 + wm * 64 + m * 16 + crow + j;
        int64_t col = bn * 128 + wn * 64 + n * 16 + ccol;
        storeC(&C[row * ldc + col], acc[m][n][j]);
      }
}

// ---------------------------------------------------------------------------
// 256x256 8-phase bf16 GEMM. C[m,n] = sum_k A[m,k]*B[n,k].
// BK=64, 8 waves (2x4), per-wave 128x64 out = acc[8][4] frags of 16x16x32.
// LDS 128 KiB: As/Bs [2 dbuf][256][64] bf16, XOR-swizzle byte^=((row&7)<<4).
//
// R7 change (single variable vs R5): ALL 24 ds_read_b128 per K-tile are
// issued up-front in phase 1, before the first MFMA barrier. MFMA q1 waits
// only on its own 12 registers (compiler-counted lgkm); the other 12 reads
// drain UNDER q1/q2's MFMA bursts, keeping the LDS pipe busy through the
// group (it previously idled ~50%: 1940 cyc/K-tile vs the 1000-cyc LDS
// floor at 256 B/cy). WAR safety unchanged: b23 is consumed by q2, so all
// waves' B reads are serviced before they pass p2's closing barrier, and
// stageB(g+2) into the current B region issues only after that barrier.
// ---------------------------------------------------------------------------
template <typename OUT_T, typename OUT2_T>
__global__ __launch_bounds__(512, 2)
void gemm256(const bf16_t* __restrict__ A, const bf16_t* __restrict__ B,
             OUT_T* __restrict__ C0, OUT2_T* __restrict__ C1,
             int K, int lda, int ldb, int ldc,
             int64_t b_batch_stride, int bm_per_batch,
             int64_t za_off, int64_t zb_off)
{
  __shared__ bf16_t As[2][256][64];
  __shared__ bf16_t Bs[2][256][64];

  const int tid  = threadIdx.x;
  const int wid  = tid >> 6;     // 0..7
  const int lane = tid & 63;
  const int wm = wid >> 2;
  const int wn = wid & 3;
  const int64_t bm = blockIdx.x;
  const int64_t bn = blockIdx.y;
  const int z = blockIdx.z;

  const bf16_t* Ap = A + (int64_t)z * za_off;
  const bf16_t* Bp = B + (bm / bm_per_batch) * b_batch_stride
                       + (int64_t)z * zb_off;

  const int srow  = wid * 16 + (lane >> 3);
  const int sslot = (lane & 7) ^ (lane >> 3);
  const int64_t lda64 = lda, ldb64 = ldb;
  const bf16_t* Ag = Ap + (bm * 256 + srow) * lda64 + sslot * 8;
  const bf16_t* Bg = Bp + (bn * 256 + srow) * ldb64 + sslot * 8;

  auto stageA = [&](int buf, int t, int h) {
    const bf16_t* src = Ag + (int64_t)(h * 128) * lda64 + t * 64;
    char* dst = (char*)&As[buf][h * 128 + wid * 16][0];
    __builtin_amdgcn_global_load_lds((const gv_t*)src, (lv_t*)dst, 16, 0, 0);
    __builtin_amdgcn_global_load_lds((const gv_t*)(src + 8 * lda64),
                                     (lv_t*)(dst + 1024), 16, 0, 0);
  };
  auto stageB = [&](int buf, int t, int h) {
    const bf16_t* src = Bg + (int64_t)(h * 128) * ldb64 + t * 64;
    char* dst = (char*)&Bs[buf][h * 128 + wid * 16][0];
    __builtin_amdgcn_global_load_lds((const gv_t*)src, (lv_t*)dst, 16, 0, 0);
    __builtin_amdgcn_global_load_lds((const gv_t*)(src + 8 * ldb64),
                                     (lv_t*)(dst + 1024), 16, 0, 0);
  };

  const int frow   = lane & 15;
  const int fcol16 = lane >> 4;
  const int xorv   = (lane & 7) << 4;
  const int ck0 = (fcol16 * 16) ^ xorv;
  const int ck1 = (64 + fcol16 * 16) ^ xorv;
  const int arowb = (wm * 128 + frow) * 128;
  const int browb = (wn * 64  + frow) * 128;

  f32x4 acc[8][4];
  #pragma unroll
  for (int m = 0; m < 8; m++)
    #pragma unroll
    for (int n = 0; n < 4; n++) acc[m][n] = f32x4{0.f, 0.f, 0.f, 0.f};

  const int NT = K >> 6;

  stageA(0, 0, 0); stageA(0, 0, 1);
  stageB(0, 0, 0); stageB(0, 0, 1);
  stageB(1, 1, 0); stageB(1, 1, 1);
  asm volatile("s_waitcnt vmcnt(4)" ::: "memory");
  __builtin_amdgcn_s_barrier();
  __builtin_amdgcn_sched_barrier(0);

  bf16x8 a[8][2], bb[4][2];

  for (int g = 0; g < NT; ++g) {
    const int buf = g & 1;
    const char* lA = (const char*)&As[buf][0][0];
    const char* lB = (const char*)&Bs[buf][0][0];

    // ======== phase 1: ALL frag reads (24 b128); stage A(g+1).h0 ========
    #pragma unroll
    for (int m = 0; m < 8; m++) {
      a[m][0] = *(const bf16x8*)(lA + arowb + m * 2048 + ck0);
      a[m][1] = *(const bf16x8*)(lA + arowb + m * 2048 + ck1);
    }
    #pragma unroll
    for (int n = 0; n < 4; n++) {
      bb[n][0] = *(const bf16x8*)(lB + browb + n * 2048 + ck0);
      bb[n][1] = *(const bf16x8*)(lB + browb + n * 2048 + ck1);
    }
    if (g + 1 < NT) stageA(buf ^ 1, g + 1, 0);
    __builtin_amdgcn_s_barrier();
    __builtin_amdgcn_s_setprio(1);
    #pragma unroll
    for (int m = 0; m < 4; m++)
      #pragma unroll
      for (int n = 0; n < 2; n++)
        #pragma unroll
        for (int k = 0; k < 2; k++)
          acc[m][n] = __builtin_amdgcn_mfma_f32_16x16x32_bf16(a[m][k], bb[n][k],
                                                              acc[m][n], 0, 0, 0);
    __builtin_amdgcn_s_setprio(0);
    __builtin_amdgcn_s_barrier();

    // ======== phase 2: MFMA q2 (m0-3 x n2-3); stage A(g+1).h1 ========
    if (g + 1 < NT) stageA(buf ^ 1, g + 1, 1);
    __builtin_amdgcn_s_barrier();
    __builtin_amdgcn_s_setprio(1);
    #pragma unroll
    for (int m = 0; m < 4; m++)
      #pragma unroll
      for (int n = 2; n < 4; n++)
        #pragma unroll
        for (int k = 0; k < 2; k++)
          acc[m][n] = __builtin_amdgcn_mfma_f32_16x16x32_bf16(a[m][k], bb[n][k],
                                                              acc[m][n], 0, 0, 0);
    __builtin_amdgcn_s_setprio(0);
    __builtin_amdgcn_s_barrier();

    // ======== phase 3: MFMA q3 (m4-7 x n0-1); stage B(g+2).h0 ========
    if (g + 2 < NT) stageB(buf, g + 2, 0);
    __builtin_amdgcn_s_barrier();
    __builtin_amdgcn_s_setprio(1);
    #pragma unroll
    for (int m = 4; m < 8; m++)
      #pragma unroll
      for (int n = 0; n < 2; n++)
        #pragma unroll
        for (int k = 0; k < 2; k++)
          acc[m][n] = __builtin_amdgcn_mfma_f32_16x16x32_bf16(
              a[m][k], bb[n][k], acc[m][n], 0, 0, 0);
    __builtin_amdgcn_s_setprio(0);
    __builtin_amdgcn_s_barrier();

    // ======== phase 4: MFMA q4 (m4-7 x n2-3); stage B(g+2).h1; vmcnt ========
    if (g + 2 < NT) stageB(buf, g + 2, 1);
    __builtin_amdgcn_s_barrier();
    __builtin_amdgcn_s_setprio(1);
    #pragma unroll
    for (int m = 4; m < 8; m++)
      #pragma unroll
      for (int n = 2; n < 4; n++)
        #pragma unroll
        for (int k = 0; k < 2; k++)
          acc[m][n] = __builtin_amdgcn_mfma_f32_16x16x32_bf16(
              a[m][k], bb[n][k], acc[m][n], 0, 0, 0);
    __builtin_amdgcn_s_setprio(0);
    if (g + 2 < NT) {
      asm volatile("s_waitcnt vmcnt(4)" ::: "memory");
    } else {
      asm volatile("s_waitcnt vmcnt(0)" ::: "memory");
    }
    __builtin_amdgcn_s_barrier();
    __builtin_amdgcn_sched_barrier(0);
  }

  const int crow = (lane >> 4) * 4;
  const int ccol = lane & 15;
  if (z == 0) {
    #pragma unroll
    for (int m = 0; m < 8; m++)
      #pragma unroll
      for (int n = 0; n < 4; n++)
        #pragma unroll
        for (int j = 0; j < 4; j++) {
          int64_t row = bm * 256 + wm * 128 + m * 16 + crow + j;
          int64_t col = bn * 256 + wn * 64 + n * 16 + ccol;
          storeC(&C0[row * (int64_t)ldc + col], acc[m][n][j]);
        }
  } else {
    #pragma unroll
    for (int m = 0; m < 8; m++)
      #pragma unroll
      for (int n = 0; n < 4; n++)
        #pragma unroll
        for (int j = 0; j < 4; j++) {
          int64_t row = bm * 256 + wm * 128 + m * 16 + crow + j;
          int64_t col = bn * 256 + wn * 64 + n * 16 + ccol;
          storeC(&C1[row * (int64_t)ldc + col], acc[m][n][j]);
        }
  }
}

// ---------------------------------------------------------------------------
// Row softmax IN PLACE: fp16 raw scores [rows x 4096] -> normalized bf16 P.
// ---------------------------------------------------------------------------
__global__ __launch_bounds__(256)
void softmax_rows(__half* __restrict__ SP)
{
  const int64_t row = blockIdx.x;
  __half* s = SP + row * 4096;
  bf16_t* p = (bf16_t*)s;
  const int tid = threadIdx.x;
  const float scale = 0.03125f;  // 1/sqrt(1024)

  float v[16];
  float vmax = -3.4e38f;
  #pragma unroll
  for (int i = 0; i < 4; i++) {
    uint2 raw = *(const uint2*)(s + i * 1024 + tid * 4);
    __half2 h01 = __builtin_bit_cast(__half2, raw.x);
    __half2 h23 = __builtin_bit_cast(__half2, raw.y);
    float2 f01 = __half22float2(h01);
    float2 f23 = __half22float2(h23);
    v[i * 4 + 0] = f01.x * scale;
    v[i * 4 + 1] = f01.y * scale;
    v[i * 4 + 2] = f23.x * scale;
    v[i * 4 + 3] = f23.y * scale;
    vmax = fmaxf(vmax, fmaxf(fmaxf(v[i*4+0], v[i*4+1]),
                             fmaxf(v[i*4+2], v[i*4+3])));
  }
  #pragma unroll
  for (int o = 32; o > 0; o >>= 1) vmax = fmaxf(vmax, __shfl_xor(vmax, o));
  __shared__ float redm[4];
  __shared__ float reds[4];
  if ((tid & 63) == 0) redm[tid >> 6] = vmax;
  __syncthreads();
  vmax = fmaxf(fmaxf(redm[0], redm[1]), fmaxf(redm[2], redm[3]));

  float lsum = 0.f;
  #pragma unroll
  for (int i = 0; i < 16; i++) {
    v[i] = __expf(v[i] - vmax);
    lsum += v[i];
  }
  #pragma unroll
  for (int o = 32; o > 0; o >>= 1) lsum += __shfl_xor(lsum, o);
  if ((tid & 63) == 0) reds[tid >> 6] = lsum;
  __syncthreads();
  lsum = (reds[0] + reds[1]) + (reds[2] + reds[3]);
  const float inv = 1.0f / lsum;

  #pragma unroll
  for (int i = 0; i < 4; i++) {
    uint32_t lo = ((uint32_t)f2bf_bits(v[i*4+1] * inv) << 16) | f2bf_bits(v[i*4+0] * inv);
    uint32_t hi = ((uint32_t)f2bf_bits(v[i*4+3] * inv) << 16) | f2bf_bits(v[i*4+2] * inv);
    *(uint2*)(p + i * 1024 + tid * 4) = make_uint2(lo, hi);
  }
}

// ---------------------------------------------------------------------------
// out[i] += (float)partial_fp16[i]  (split-K reduce)
// ---------------------------------------------------------------------------
__global__ __launch_bounds__(256)
void addk_h4(float4* __restrict__ o, const uint2* __restrict__ a, int64_t n4)
{
  for (int64_t i = (int64_t)blockIdx.x * blockDim.x + threadIdx.x; i < n4;
       i += (int64_t)gridDim.x * blockDim.x) {
    float4 x = o[i];
    uint2 raw = a[i];
    __half2 h01 = __builtin_bit_cast(__half2, raw.x);
    __half2 h23 = __builtin_bit_cast(__half2, raw.y);
    float2 f01 = __half22float2(h01);
    float2 f23 = __half22float2(h23);
    x.x += f01.x; x.y += f01.y; x.z += f23.x; x.w += f23.y;
    o[i] = x;
  }
}

// ---------------------------------------------------------------------------
// ws layout (112 MiB):
//   [0,   64M): S/P fp16->bf16 [8192 x 4096]
//               overlapped early: xb [0,16M), wqkb [16M,20M), wvb [20M,22M)
//   [64M, 96M): qk bf16 [8192 x 2048] (Q|K); dead after S -> reused as
//               PV fp16 split-K partial pk16 [8192 x 1024] (16 MiB)
//   [96M,112M): vt bf16 [1024 x 8192]
// ---------------------------------------------------------------------------
extern "C" void kernel_launch(void* const* d_in, const int* in_sizes, int n_in,
                              void* d_out, int out_size, void* d_ws, size_t ws_size,
                              hipStream_t stream) {
  const float* x  = (const float*)d_in[0];
  const float* wq = (const float*)d_in[1];
  const float* wk = (const float*)d_in[2];
  const float* wv = (const float*)d_in[3];
  float* out = (float*)d_out;

  char* ws = (char*)d_ws;
  bf16_t* xb   = (bf16_t*)ws;
  bf16_t* wqkb = (bf16_t*)(ws + (16LL << 20));
  bf16_t* wvb  = (bf16_t*)(ws + (20LL << 20));
  __half* S    = (__half*)ws;
  bf16_t* qk   = (bf16_t*)(ws + (64LL << 20));
  __half* pk16 = (__half*)(ws + (64LL << 20));  // PV split-K partial (16 MiB)
  bf16_t* vt   = (bf16_t*)(ws + (96LL << 20));

  const int NO_BATCH = 1 << 30;

  convert_all<<<2048, 256, 0, stream>>>(x, wq, wk, wv, xb, wqkb, wvb);

  // qk[8192 x 2048] = xb * wqkb^T
  gemm256<bf16_t, bf16_t><<<dim3(32, 8, 1), 512, 0, stream>>>(
      xb, wqkb, qk, qk, 1024, 1024, 1024, 2048, 0, NO_BATCH, 0, 0);

  // vt[1024 x 8192] = wvb * xb^T
  gemm_bt<bf16_t><<<dim3(8, 64), 256, 0, stream>>>(
      wvb, xb, vt, 1024, 1024, 1024, 8192, 0, NO_BATCH);

  // S[8192 x 4096] = Q * K_b^T (raw fp16), batch b = bm/16
  gemm256<__half, __half><<<dim3(32, 16, 1), 512, 0, stream>>>(
      qk, qk + 1024, S, S, 1024, 2048, 2048, 4096, 4096LL * 2048, 16, 0, 0);

  softmax_rows<<<8192, 256, 0, stream>>>(S);

  // out[8192 x 1024] = P * V_b^T, split-K (z=0 -> out f32, z=1 -> pk16 fp16)
  gemm256<float, __half><<<dim3(32, 4, 2), 512, 0, stream>>>(
      (const bf16_t*)S, vt, out, pk16, 2048, 4096, 8192, 1024,
      4096, 16, 2048, 2048);

  addk_h4<<<2048, 256, 0, stream>>>((float4*)out, (const uint2*)pk16,
                                    8192LL * 1024 / 4);
}

// Round 8
// 230.605 us; speedup vs baseline: 1.0876x; 1.0725x over previous
//
#include <hip/hip_runtime.h>
#include <hip/hip_bf16.h>
#include <hip/hip_fp16.h>
#include <stdint.h>

typedef __bf16 bf16_t;
typedef __bf16 bf16x8 __attribute__((ext_vector_type(8)));
typedef float f32x4 __attribute__((ext_vector_type(4)));

typedef __attribute__((address_space(1))) void gv_t;
typedef __attribute__((address_space(3))) void lv_t;

__device__ inline unsigned short f2bf_bits(float f) {
  uint32_t u = __float_as_uint(f);
  u += 0x7FFFu + ((u >> 16) & 1u);   // RNE
  return (unsigned short)(u >> 16);
}
__device__ inline bf16_t f2bf(float f) {
  unsigned short h = f2bf_bits(f);
  return __builtin_bit_cast(bf16_t, h);
}

__device__ inline void storeC(float* p, float v) { *p = v; }
__device__ inline void storeC(bf16_t* p, float v) { *p = f2bf(v); }
__device__ inline void storeC(__half* p, float v) { *p = __float2half(v); }

// ---------------------------------------------------------------------------
// fp32 -> bf16 conversion for x, Wq, Wk (packed together), Wv
// ---------------------------------------------------------------------------
__global__ __launch_bounds__(256)
void convert_all(const float* __restrict__ x, const float* __restrict__ wq,
                 const float* __restrict__ wk, const float* __restrict__ wv,
                 bf16_t* __restrict__ xb, bf16_t* __restrict__ wqkb,
                 bf16_t* __restrict__ wvb)
{
  const int64_t NX = 8192LL * 1024, NW = 1024LL * 1024;
  const int64_t total4 = (NX + 3 * NW) >> 2;
  for (int64_t i = (int64_t)blockIdx.x * blockDim.x + threadIdx.x; i < total4;
       i += (int64_t)gridDim.x * blockDim.x) {
    int64_t e = i << 2;
    const float* src; bf16_t* dst; int64_t off;
    if (e < NX)               { src = x;  dst = xb;         off = e; }
    else if (e < NX + NW)     { src = wq; dst = wqkb;       off = e - NX; }
    else if (e < NX + 2 * NW) { src = wk; dst = wqkb + NW;  off = e - NX - NW; }
    else                      { src = wv; dst = wvb;        off = e - NX - 2 * NW; }
    float4 f = *(const float4*)(src + off);
    uint32_t lo = ((uint32_t)f2bf_bits(f.y) << 16) | f2bf_bits(f.x);
    uint32_t hi = ((uint32_t)f2bf_bits(f.w) << 16) | f2bf_bits(f.z);
    *(uint2*)(dst + off) = make_uint2(lo, hi);
  }
}

// ---------------------------------------------------------------------------
// Legacy 128x128 2-phase gemm (kept for the small Vt projection only).
// ---------------------------------------------------------------------------
template <typename OUT_T>
__global__ __launch_bounds__(256)
void gemm_bt(const bf16_t* __restrict__ A, const bf16_t* __restrict__ B,
             OUT_T* __restrict__ C, int K, int lda, int ldb, int ldc,
             int64_t b_batch_stride, int bm_per_batch)
{
  __shared__ bf16_t As[2][128 * 32];
  __shared__ bf16_t Bs[2][128 * 32];
  const int tid  = threadIdx.x;
  const int wid  = tid >> 6;
  const int lane = tid & 63;
  const int wm = wid >> 1, wn = wid & 1;
  const int64_t bm = blockIdx.x;
  const int64_t bn = blockIdx.y;

  const bf16_t* Bb = B + (bm / bm_per_batch) * b_batch_stride;

  const int c0row = (wid * 2 + 0) * 16 + (lane >> 2);
  const int c1row = (wid * 2 + 1) * 16 + (lane >> 2);
  const int scol  = (lane & 3) * 8;

  const bf16_t* Ar0 = A  + (bm * 128 + c0row) * lda + scol;
  const bf16_t* Ar1 = A  + (bm * 128 + c1row) * lda + scol;
  const bf16_t* Br0 = Bb + (bn * 128 + c0row) * ldb + scol;
  const bf16_t* Br1 = Bb + (bn * 128 + c1row) * ldb + scol;

  const int ad0 = (wid * 2 + 0) * 512;
  const int ad1 = (wid * 2 + 1) * 512;

  const int frow = lane & 15;
  const int fk   = (lane >> 4) * 8;
  const int aoff = (wm * 64 + frow) * 32 + fk;
  const int boff = (wn * 64 + frow) * 32 + fk;

  f32x4 acc[4][4];
  #pragma unroll
  for (int m = 0; m < 4; m++)
    #pragma unroll
    for (int n = 0; n < 4; n++) acc[m][n] = f32x4{0.f, 0.f, 0.f, 0.f};

  auto stage = [&](int buf, int k0) {
    __builtin_amdgcn_global_load_lds((const gv_t*)(Ar0 + k0),
                                     (lv_t*)(&As[buf][ad0]), 16, 0, 0);
    __builtin_amdgcn_global_load_lds((const gv_t*)(Ar1 + k0),
                                     (lv_t*)(&As[buf][ad1]), 16, 0, 0);
    __builtin_amdgcn_global_load_lds((const gv_t*)(Br0 + k0),
                                     (lv_t*)(&Bs[buf][ad0]), 16, 0, 0);
    __builtin_amdgcn_global_load_lds((const gv_t*)(Br1 + k0),
                                     (lv_t*)(&Bs[buf][ad1]), 16, 0, 0);
  };

  stage(0, 0);
  __syncthreads();
  int cur = 0;
  for (int k0 = 0; k0 < K; k0 += 32) {
    if (k0 + 32 < K) stage(cur ^ 1, k0 + 32);

    bf16x8 af[4], bfr[4];
    #pragma unroll
    for (int m = 0; m < 4; m++)
      af[m] = *(const bf16x8*)(&As[cur][aoff + m * 16 * 32]);
    #pragma unroll
    for (int n = 0; n < 4; n++)
      bfr[n] = *(const bf16x8*)(&Bs[cur][boff + n * 16 * 32]);
    #pragma unroll
    for (int m = 0; m < 4; m++)
      #pragma unroll
      for (int n = 0; n < 4; n++)
        acc[m][n] = __builtin_amdgcn_mfma_f32_16x16x32_bf16(af[m], bfr[n],
                                                            acc[m][n], 0, 0, 0);
    __syncthreads();
    cur ^= 1;
  }

  const int crow = (lane >> 4) * 4;
  const int ccol = lane & 15;
  #pragma unroll
  for (int m = 0; m < 4; m++)
    #pragma unroll
    for (int n = 0; n < 4; n++)
      #pragma unroll
      for (int j = 0; j < 4; j++) {
        int64_t row = bm * 128 + wm * 64 + m * 16 + crow + j;
        int64_t col = bn * 128 + wn * 64 + n * 16 + ccol;
        storeC(&C[row * ldc + col], acc[m][n][j]);
      }
}

// ---------------------------------------------------------------------------
// 256x256 bf16 GEMM, 1-barrier-per-K-tile pipelined loop (R8).
// BK=64, 8 waves (2x4), per-wave 128x64 out = acc[8][4] frags of 16x16x32.
// LDS 128 KiB: As/Bs [2 dbuf][256][64] bf16, XOR-swizzle byte^=((row&7)<<4).
//
// Why (R4/R5/R7 post-mortem): the 8-barrier phase lockstep serialized the
// LDS-read floor (~1700 cyc/K-tile/CU) against the MFMA floor (~2060
// cyc/K-tile/SIMD = 2 waves x 64 MFMA x 16.1 cyc). New loop per K-tile:
//   issue all 24 ds_reads (k0 frags first) | issue 4 stages -> other buf |
//   64 MFMA (compiler-counted lgkm: k1 reads + staging drain under k0 burst)
//   | vmcnt(0) | s_barrier
// Race audit: staging into buf^1 is WAR-safe (each wave's buf^1 reads were
// consumed by its g-1 MFMAs before it crossed the g-1 barrier); reads of
// buf[g] are RAW-safe (every wave's vmcnt(0) precedes the shared barrier,
// so all staging landed before any wave proceeds).
// ---------------------------------------------------------------------------
template <typename OUT_T, typename OUT2_T>
__global__ __launch_bounds__(512, 2)
void gemm256(const bf16_t* __restrict__ A, const bf16_t* __restrict__ B,
             OUT_T* __restrict__ C0, OUT2_T* __restrict__ C1,
             int K, int lda, int ldb, int ldc,
             int64_t b_batch_stride, int bm_per_batch,
             int64_t za_off, int64_t zb_off)
{
  __shared__ bf16_t As[2][256][64];
  __shared__ bf16_t Bs[2][256][64];

  const int tid  = threadIdx.x;
  const int wid  = tid >> 6;     // 0..7
  const int lane = tid & 63;
  const int wm = wid >> 2;
  const int wn = wid & 3;
  const int64_t bm = blockIdx.x;
  const int64_t bn = blockIdx.y;
  const int z = blockIdx.z;

  const bf16_t* Ap = A + (int64_t)z * za_off;
  const bf16_t* Bp = B + (bm / bm_per_batch) * b_batch_stride
                       + (int64_t)z * zb_off;

  // staging (write side): pre-swizzled global source, linear LDS dest
  const int srow  = wid * 16 + (lane >> 3);
  const int sslot = (lane & 7) ^ (lane >> 3);
  const int64_t lda64 = lda, ldb64 = ldb;
  const bf16_t* Ag = Ap + (bm * 256 + srow) * lda64 + sslot * 8;
  const bf16_t* Bg = Bp + (bn * 256 + srow) * ldb64 + sslot * 8;

  auto stageA = [&](int buf, int t, int h) {
    const bf16_t* src = Ag + (int64_t)(h * 128) * lda64 + t * 64;
    char* dst = (char*)&As[buf][h * 128 + wid * 16][0];
    __builtin_amdgcn_global_load_lds((const gv_t*)src, (lv_t*)dst, 16, 0, 0);
    __builtin_amdgcn_global_load_lds((const gv_t*)(src + 8 * lda64),
                                     (lv_t*)(dst + 1024), 16, 0, 0);
  };
  auto stageB = [&](int buf, int t, int h) {
    const bf16_t* src = Bg + (int64_t)(h * 128) * ldb64 + t * 64;
    char* dst = (char*)&Bs[buf][h * 128 + wid * 16][0];
    __builtin_amdgcn_global_load_lds((const gv_t*)src, (lv_t*)dst, 16, 0, 0);
    __builtin_amdgcn_global_load_lds((const gv_t*)(src + 8 * ldb64),
                                     (lv_t*)(dst + 1024), 16, 0, 0);
  };

  // fragment read coords (swizzled)
  const int frow   = lane & 15;
  const int fcol16 = lane >> 4;
  const int xorv   = (lane & 7) << 4;
  const int ck0 = (fcol16 * 16) ^ xorv;
  const int ck1 = (64 + fcol16 * 16) ^ xorv;
  const int arowb = (wm * 128 + frow) * 128;
  const int browb = (wn * 64  + frow) * 128;

  f32x4 acc[8][4];
  #pragma unroll
  for (int m = 0; m < 8; m++)
    #pragma unroll
    for (int n = 0; n < 4; n++) acc[m][n] = f32x4{0.f, 0.f, 0.f, 0.f};

  const int NT = K >> 6;

  // prologue: stage T0 only; wait it; barrier
  stageA(0, 0, 0); stageA(0, 0, 1);
  stageB(0, 0, 0); stageB(0, 0, 1);
  asm volatile("s_waitcnt vmcnt(0)" ::: "memory");
  __builtin_amdgcn_s_barrier();
  __builtin_amdgcn_sched_barrier(0);

  bf16x8 a[8][2], bb[4][2];

  for (int g = 0; g < NT; ++g) {
    const int buf = g & 1;
    const char* lA = (const char*)&As[buf][0][0];
    const char* lB = (const char*)&Bs[buf][0][0];

    // ---- all 24 frag reads, k0 frags first (k1 drains under k0 MFMAs) ----
    #pragma unroll
    for (int m = 0; m < 8; m++)
      a[m][0] = *(const bf16x8*)(lA + arowb + m * 2048 + ck0);
    #pragma unroll
    for (int n = 0; n < 4; n++)
      bb[n][0] = *(const bf16x8*)(lB + browb + n * 2048 + ck0);
    #pragma unroll
    for (int m = 0; m < 8; m++)
      a[m][1] = *(const bf16x8*)(lA + arowb + m * 2048 + ck1);
    #pragma unroll
    for (int n = 0; n < 4; n++)
      bb[n][1] = *(const bf16x8*)(lB + browb + n * 2048 + ck1);

    // ---- stage next K-tile into the other buffer (WAR-safe, see header) ----
    if (g + 1 < NT) {
      stageA(buf ^ 1, g + 1, 0); stageA(buf ^ 1, g + 1, 1);
      stageB(buf ^ 1, g + 1, 0); stageB(buf ^ 1, g + 1, 1);
    }

    // ---- 64 MFMAs; compiler-counted lgkm waits give intra-tile overlap ----
    __builtin_amdgcn_s_setprio(1);
    #pragma unroll
    for (int k = 0; k < 2; k++)
      #pragma unroll
      for (int m = 0; m < 8; m++)
        #pragma unroll
        for (int n = 0; n < 4; n++)
          acc[m][n] = __builtin_amdgcn_mfma_f32_16x16x32_bf16(
              a[m][k], bb[n][k], acc[m][n], 0, 0, 0);
    __builtin_amdgcn_s_setprio(0);

    // ---- next tile resident + own reads consumed -> single barrier ----
    asm volatile("s_waitcnt vmcnt(0)" ::: "memory");
    __builtin_amdgcn_s_barrier();
    __builtin_amdgcn_sched_barrier(0);
  }

  // epilogue: C/D layout col=lane&15, row=(lane>>4)*4+j
  const int crow = (lane >> 4) * 4;
  const int ccol = lane & 15;
  if (z == 0) {
    #pragma unroll
    for (int m = 0; m < 8; m++)
      #pragma unroll
      for (int n = 0; n < 4; n++)
        #pragma unroll
        for (int j = 0; j < 4; j++) {
          int64_t row = bm * 256 + wm * 128 + m * 16 + crow + j;
          int64_t col = bn * 256 + wn * 64 + n * 16 + ccol;
          storeC(&C0[row * (int64_t)ldc + col], acc[m][n][j]);
        }
  } else {
    #pragma unroll
    for (int m = 0; m < 8; m++)
      #pragma unroll
      for (int n = 0; n < 4; n++)
        #pragma unroll
        for (int j = 0; j < 4; j++) {
          int64_t row = bm * 256 + wm * 128 + m * 16 + crow + j;
          int64_t col = bn * 256 + wn * 64 + n * 16 + ccol;
          storeC(&C1[row * (int64_t)ldc + col], acc[m][n][j]);
        }
  }
}

// ---------------------------------------------------------------------------
// Row softmax IN PLACE: fp16 raw scores [rows x 4096] -> normalized bf16 P.
// ---------------------------------------------------------------------------
__global__ __launch_bounds__(256)
void softmax_rows(__half* __restrict__ SP)
{
  const int64_t row = blockIdx.x;
  __half* s = SP + row * 4096;
  bf16_t* p = (bf16_t*)s;
  const int tid = threadIdx.x;
  const float scale = 0.03125f;  // 1/sqrt(1024)

  float v[16];
  float vmax = -3.4e38f;
  #pragma unroll
  for (int i = 0; i < 4; i++) {
    uint2 raw = *(const uint2*)(s + i * 1024 + tid * 4);
    __half2 h01 = __builtin_bit_cast(__half2, raw.x);
    __half2 h23 = __builtin_bit_cast(__half2, raw.y);
    float2 f01 = __half22float2(h01);
    float2 f23 = __half22float2(h23);
    v[i * 4 + 0] = f01.x * scale;
    v[i * 4 + 1] = f01.y * scale;
    v[i * 4 + 2] = f23.x * scale;
    v[i * 4 + 3] = f23.y * scale;
    vmax = fmaxf(vmax, fmaxf(fmaxf(v[i*4+0], v[i*4+1]),
                             fmaxf(v[i*4+2], v[i*4+3])));
  }
  #pragma unroll
  for (int o = 32; o > 0; o >>= 1) vmax = fmaxf(vmax, __shfl_xor(vmax, o));
  __shared__ float redm[4];
  __shared__ float reds[4];
  if ((tid & 63) == 0) redm[tid >> 6] = vmax;
  __syncthreads();
  vmax = fmaxf(fmaxf(redm[0], redm[1]), fmaxf(redm[2], redm[3]));

  float lsum = 0.f;
  #pragma unroll
  for (int i = 0; i < 16; i++) {
    v[i] = __expf(v[i] - vmax);
    lsum += v[i];
  }
  #pragma unroll
  for (int o = 32; o > 0; o >>= 1) lsum += __shfl_xor(lsum, o);
  if ((tid & 63) == 0) reds[tid >> 6] = lsum;
  __syncthreads();
  lsum = (reds[0] + reds[1]) + (reds[2] + reds[3]);
  const float inv = 1.0f / lsum;

  #pragma unroll
  for (int i = 0; i < 4; i++) {
    uint32_t lo = ((uint32_t)f2bf_bits(v[i*4+1] * inv) << 16) | f2bf_bits(v[i*4+0] * inv);
    uint32_t hi = ((uint32_t)f2bf_bits(v[i*4+3] * inv) << 16) | f2bf_bits(v[i*4+2] * inv);
    *(uint2*)(p + i * 1024 + tid * 4) = make_uint2(lo, hi);
  }
}

// ---------------------------------------------------------------------------
// out[i] += (float)partial_fp16[i]  (split-K reduce)
// ---------------------------------------------------------------------------
__global__ __launch_bounds__(256)
void addk_h4(float4* __restrict__ o, const uint2* __restrict__ a, int64_t n4)
{
  for (int64_t i = (int64_t)blockIdx.x * blockDim.x + threadIdx.x; i < n4;
       i += (int64_t)gridDim.x * blockDim.x) {
    float4 x = o[i];
    uint2 raw = a[i];
    __half2 h01 = __builtin_bit_cast(__half2, raw.x);
    __half2 h23 = __builtin_bit_cast(__half2, raw.y);
    float2 f01 = __half22float2(h01);
    float2 f23 = __half22float2(h23);
    x.x += f01.x; x.y += f01.y; x.z += f23.x; x.w += f23.y;
    o[i] = x;
  }
}

// ---------------------------------------------------------------------------
// ws layout (112 MiB):
//   [0,   64M): S/P fp16->bf16 [8192 x 4096]
//               overlapped early: xb [0,16M), wqkb [16M,20M), wvb [20M,22M)
//   [64M, 96M): qk bf16 [8192 x 2048] (Q|K); dead after S -> reused as
//               PV fp16 split-K partial pk16 [8192 x 1024] (16 MiB)
//   [96M,112M): vt bf16 [1024 x 8192]
// ---------------------------------------------------------------------------
extern "C" void kernel_launch(void* const* d_in, const int* in_sizes, int n_in,
                              void* d_out, int out_size, void* d_ws, size_t ws_size,
                              hipStream_t stream) {
  const float* x  = (const float*)d_in[0];
  const float* wq = (const float*)d_in[1];
  const float* wk = (const float*)d_in[2];
  const float* wv = (const float*)d_in[3];
  float* out = (float*)d_out;

  char* ws = (char*)d_ws;
  bf16_t* xb   = (bf16_t*)ws;
  bf16_t* wqkb = (bf16_t*)(ws + (16LL << 20));
  bf16_t* wvb  = (bf16_t*)(ws + (20LL << 20));
  __half* S    = (__half*)ws;
  bf16_t* qk   = (bf16_t*)(ws + (64LL << 20));
  __half* pk16 = (__half*)(ws + (64LL << 20));  // PV split-K partial (16 MiB)
  bf16_t* vt   = (bf16_t*)(ws + (96LL << 20));

  const int NO_BATCH = 1 << 30;

  convert_all<<<2048, 256, 0, stream>>>(x, wq, wk, wv, xb, wqkb, wvb);

  // qk[8192 x 2048] = xb * wqkb^T
  gemm256<bf16_t, bf16_t><<<dim3(32, 8, 1), 512, 0, stream>>>(
      xb, wqkb, qk, qk, 1024, 1024, 1024, 2048, 0, NO_BATCH, 0, 0);

  // vt[1024 x 8192] = wvb * xb^T
  gemm_bt<bf16_t><<<dim3(8, 64), 256, 0, stream>>>(
      wvb, xb, vt, 1024, 1024, 1024, 8192, 0, NO_BATCH);

  // S[8192 x 4096] = Q * K_b^T (raw fp16), batch b = bm/16
  gemm256<__half, __half><<<dim3(32, 16, 1), 512, 0, stream>>>(
      qk, qk + 1024, S, S, 1024, 2048, 2048, 4096, 4096LL * 2048, 16, 0, 0);

  softmax_rows<<<8192, 256, 0, stream>>>(S);

  // out[8192 x 1024] = P * V_b^T, split-K (z=0 -> out f32, z=1 -> pk16 fp16)
  gemm256<float, __half><<<dim3(32, 4, 2), 512, 0, stream>>>(
      (const bf16_t*)S, vt, out, pk16, 2048, 4096, 8192, 1024,
      4096, 16, 2048, 2048);

  addk_h4<<<2048, 256, 0, stream>>>((float4*)out, (const uint2*)pk16,
                                    8192LL * 1024 / 4);
}